// Round 4
// baseline (1622.564 us; speedup 1.0000x reference)
//
#include <hip/hip_runtime.h>
#include <stdint.h>

#define NROWS 16384
#define QNUM  8192
#define ED    512
#define BM    128
#define BN    128
#define KTILES 8           // K tiles of 64 elements
#define QBLKS  (QNUM / BN) // 64
#define DELTA  0.008f

typedef __bf16 bf16x8 __attribute__((ext_vector_type(8)));
typedef float  f32x4  __attribute__((ext_vector_type(4)));

static __device__ __forceinline__ unsigned f2b1(float f) {
    unsigned u = __float_as_uint(f);
    return (u + 0x7FFFu + ((u >> 16) & 1u)) >> 16;   // RNE fp32 -> bf16
}
static __device__ __forceinline__ unsigned f2b2(float lo, float hi) {
    return f2b1(lo) | (f2b1(hi) << 16);
}

// keep top-2 (smallest val, tie -> smallest idx)
static __device__ __forceinline__ void ins2(float& v1, int& q1, float& v2, int& q2,
                                            float s, int q) {
    if (s < v1 || (s == v1 && q < q1)) { v2 = v1; q2 = q1; v1 = s; q1 = q; }
    else if (s < v2 || (s == v2 && q < q2)) { v2 = s; q2 = q; }
}

// ---------------- prep: fp32 -> bf16 (RNE), 8 elems/thread ----------------
__global__ __launch_bounds__(256) void k_prep_bf16(const float* __restrict__ src,
                                                   unsigned* __restrict__ dst) {
    size_t t = (size_t)blockIdx.x * 256 + threadIdx.x;
    const float4* p = (const float4*)(src + t * 8);
    float4 a = p[0], b = p[1];
    uint4 o;
    o.x = f2b2(a.x, a.y); o.y = f2b2(a.z, a.w);
    o.z = f2b2(b.x, b.y); o.w = f2b2(b.z, b.w);
    ((uint4*)dst)[t] = o;
}

// ---------------- numpy-pairwise fp32 sum of squares per 512-row ----------------
#define SROWS 32
#define SSTRIDE 520
__global__ __launch_bounds__(256) void k_sumsq_np(const float* __restrict__ src,
                                                  float* __restrict__ dst) {
    __shared__ float ld[SROWS * SSTRIDE];
    const int t = threadIdx.x;
    const size_t base = (size_t)blockIdx.x * SROWS * ED;
    #pragma unroll
    for (int k = 0; k < 16; ++k) {
        int u = k * 256 + t;          // float4 index within the 32-row slab
        int row = u >> 7;             // 128 float4 per row
        int c4  = u & 127;
        float4 v = ((const float4*)(src + base))[u];
        float* d = ld + row * SSTRIDE + c4 * 4;
        d[0] = v.x; d[1] = v.y; d[2] = v.z; d[3] = v.w;
    }
    __syncthreads();
    const int row = t >> 3, j = t & 7;
    const float* a = ld + row * SSTRIDE;
    float B[4];
    #pragma unroll
    for (int b = 0; b < 4; ++b) {
        const float* p = a + b * 128 + j;
        float r = __fmul_rn(p[0], p[0]);
        #pragma unroll
        for (int i = 1; i < 16; ++i) {
            float q = p[8 * i];
            r = __fadd_rn(r, __fmul_rn(q, q));
        }
        float t1 = __fadd_rn(r,  __shfl_xor(r,  1, 64));
        float t2 = __fadd_rn(t1, __shfl_xor(t1, 2, 64));
        B[b]     = __fadd_rn(t2, __shfl_xor(t2, 4, 64));
    }
    if (j == 0)
        dst[(size_t)blockIdx.x * SROWS + row] =
            __fadd_rn(__fadd_rn(B[0], B[1]), __fadd_rn(B[2], B[3]));
}

// ---------------- phase 1: barrier-free direct-to-register bf16 MFMA + top-2 ----------------
// No LDS staging, no K-loop __syncthreads: each lane global-loads its own MFMA
// fragments (16 B dwordx4, L2-resident inputs). Compiler software-pipelines the
// fully-unrolled K-loop with fine-grained vmcnt — the overlap the 2-barrier
// structure could not express (R3: 85% stall, MfmaUtil 3.8%).
__global__ __launch_bounds__(256) void k_gemm_top2(
        const unsigned short* __restrict__ xb,
        const unsigned short* __restrict__ wb,
        const float* __restrict__ wsqf,
        uint4* __restrict__ partial) {
    __shared__ uint4 red[2][BM];

    const int t  = threadIdx.x;
    const int wv = t >> 6;
    const int l  = t & 63;
    const int c  = l & 15;   // MFMA col / A-row lane
    const int g  = l >> 4;   // MFMA quad
    const int RB = (wv >> 1) * 64;  // wave row base in block tile
    const int CB = (wv & 1) * 64;   // wave col base

    // XCD-aware swizzle: id%8 = XCD (round-robin dispatch). XCD k owns q-panels
    // [k*8, k*8+8) -> 1 MB of B stays L2-resident per XCD; A-slabs stream and
    // are reused 8x consecutively within an XCD.
    const int id = blockIdx.x;
    const int qb = (id & 7) * 8 + ((id >> 3) & 7);  // 0..63
    const int rb = id >> 6;                          // 0..127
    const int q0 = qb * BN;
    const int r0 = rb * BM;

    f32x4 acc[4][4];
    #pragma unroll
    for (int i = 0; i < 4; ++i)
        #pragma unroll
        for (int j = 0; j < 4; ++j)
            acc[i][j] = (f32x4){0.f, 0.f, 0.f, 0.f};

    const unsigned short* ap = xb + (size_t)(r0 + RB + c) * ED;
    const unsigned short* bp = wb + (size_t)(q0 + CB + c) * ED;

    #pragma unroll
    for (int kt = 0; kt < KTILES; ++kt) {
        bf16x8 af[2][4], bfv[2][4];
        #pragma unroll
        for (int s = 0; s < 2; ++s) {
            const int ko = kt * 64 + (s * 4 + g) * 8;   // K element offset
            #pragma unroll
            for (int i = 0; i < 4; ++i)
                af[s][i] = *(const bf16x8*)(ap + (size_t)i * 16 * ED + ko);
            #pragma unroll
            for (int j = 0; j < 4; ++j)
                bfv[s][j] = *(const bf16x8*)(bp + (size_t)j * 16 * ED + ko);
        }
        #pragma unroll
        for (int s = 0; s < 2; ++s)
            #pragma unroll
            for (int i = 0; i < 4; ++i)
                #pragma unroll
                for (int j = 0; j < 4; ++j)
                    acc[i][j] = __builtin_amdgcn_mfma_f32_16x16x32_bf16(af[s][i], bfv[s][j], acc[i][j], 0, 0, 0);
    }

    // epilogue (fused, low-liveness): per owned row, top-2 over 4 col groups,
    // 16-lane butterfly, immediate LDS write (R3 fix — keeps liveness ~16 regs).
    float wsqv[4];
    #pragma unroll
    for (int j = 0; j < 4; ++j) wsqv[j] = wsqf[q0 + CB + j * 16 + c];

    #pragma unroll
    for (int i = 0; i < 4; ++i) {
        #pragma unroll
        for (int r = 0; r < 4; ++r) {
            float bv1 = 3.4e38f, bv2 = 3.4e38f;
            int   bq1 = 0x7fffffff, bq2 = 0x7fffffff;
            #pragma unroll
            for (int j = 0; j < 4; ++j) {
                const float s = fmaf(-2.0f, acc[i][j][r], wsqv[j]);
                const int   q = q0 + CB + j * 16 + c;
                ins2(bv1, bq1, bv2, bq2, s, q);
            }
            #pragma unroll
            for (int m = 1; m <= 8; m <<= 1) {
                float ov1 = __shfl_xor(bv1, m, 64);
                int   oq1 = __shfl_xor(bq1, m, 64);
                float ov2 = __shfl_xor(bv2, m, 64);
                int   oq2 = __shfl_xor(bq2, m, 64);
                ins2(bv1, bq1, bv2, bq2, ov1, oq1);
                ins2(bv1, bq1, bv2, bq2, ov2, oq2);
            }
            if (c == 0) {
                const int rl = RB + i * 16 + g * 4 + r;
                red[wv & 1][rl] = make_uint4(__float_as_uint(bv1), (unsigned)bq1,
                                             __float_as_uint(bv2), (unsigned)bq2);
            }
        }
    }
    __syncthreads();
    if (t < BM) {
        uint4 A = red[0][t], B = red[1][t];
        float av1 = __uint_as_float(A.x), av2 = __uint_as_float(A.z);
        int   aq1 = (int)A.y, aq2 = (int)A.w;
        ins2(av1, aq1, av2, aq2, __uint_as_float(B.x), (int)B.y);
        ins2(av1, aq1, av2, aq2, __uint_as_float(B.z), (int)B.w);
        partial[(size_t)(r0 + t) * QBLKS + qb] =
            make_uint4(__float_as_uint(av1), (unsigned)aq1, __float_as_uint(av2), (unsigned)aq2);
    }
}

// ---------------- phase 2: fp32-emulated (numpy semantics) rescore + gather ----------------
__global__ __launch_bounds__(256) void k_rescore(
        const uint4* __restrict__ partial,
        const float* __restrict__ x,
        const float* __restrict__ wt,
        const float* __restrict__ wsqf,
        const float* __restrict__ xsqf,
        float* __restrict__ outq,
        float* __restrict__ outi) {
    const int wv = threadIdx.x >> 6, l = threadIdx.x & 63;
    const int row = blockIdx.x * 4 + wv;

    uint4 p = partial[(size_t)row * QBLKS + l];
    float v1 = __uint_as_float(p.x), v2 = __uint_as_float(p.z);
    int   q1 = (int)p.y, q2 = (int)p.w;

    float gm = v1;
    #pragma unroll
    for (int m = 1; m < 64; m <<= 1) gm = fminf(gm, __shfl_xor(gm, m, 64));
    const float thr = gm + DELTA;

    const float4* xp = (const float4*)(x + (size_t)row * ED + l * 8);
    const float4 xa = xp[0], xbv = xp[1];
    const float xsq = xsqf[row];

    float bestv = 3.4e38f; int bestq = 0x7fffffff;
    unsigned long long mm1 = __ballot(v1 <= thr);
    unsigned long long mm2 = __ballot(v2 <= thr);
    #pragma unroll 1
    for (int slot = 0; slot < 2; ++slot) {
        unsigned long long mm = slot ? mm2 : mm1;
        while (mm) {
            const int ln = __ffsll(mm) - 1;
            mm &= mm - 1;
            const int q = __shfl(slot ? q2 : q1, ln, 64);
            const float4* wp = (const float4*)(wt + (size_t)q * ED + l * 8);
            const float4 wa = wp[0], wbv = wp[1];
            double d = (double)xa.x * wa.x + (double)xa.y * wa.y
                     + (double)xa.z * wa.z + (double)xa.w * wa.w
                     + (double)xbv.x * wbv.x + (double)xbv.y * wbv.y
                     + (double)xbv.z * wbv.z + (double)xbv.w * wbv.w;
            #pragma unroll
            for (int m = 1; m < 64; m <<= 1) d += __shfl_xor(d, m, 64);
            // numpy fp32 semantics: fl32( fl32(x_sq - 2*dot) + w_sq ), first-occurrence argmin
            const float dotf = (float)d;
            const float t1 = __fadd_rn(xsq, __fmul_rn(-2.0f, dotf));
            const float sc = __fadd_rn(t1, wsqf[q]);
            if (sc < bestv || (sc == bestv && q < bestq)) { bestv = sc; bestq = q; }
        }
    }
    const float4* wp = (const float4*)(wt + (size_t)bestq * ED + l * 8);
    float4* op = (float4*)(outq + (size_t)row * ED + l * 8);
    op[0] = wp[0]; op[1] = wp[1];
    if (l == 0) outi[row] = (float)bestq;
}

extern "C" void kernel_launch(void* const* d_in, const int* in_sizes, int n_in,
                              void* d_out, int out_size, void* d_ws, size_t ws_size,
                              hipStream_t stream) {
    (void)in_sizes; (void)n_in; (void)out_size; (void)ws_size;
    const float* x  = (const float*)d_in[0];
    const float* wt = (const float*)d_in[1];

    char* ws = (char*)d_ws;
    unsigned short* xb   = (unsigned short*)ws;               // 16,777,216 B
    unsigned short* wb   = (unsigned short*)(ws + 16777216);  //  8,388,608 B
    float*          wsqf = (float*) (ws + 25165824);          //     32,768 B
    float*          xsqf = (float*) (ws + 25198592);          //     65,536 B
    uint4*          part = (uint4*) (ws + 25264128);          // 16,777,216 B  (total ~40.1 MB)

    float* outq = (float*)d_out;
    float* outi = outq + (size_t)NROWS * ED;

    k_prep_bf16<<<4096, 256, 0, stream>>>(x,  (unsigned*)xb);
    k_prep_bf16<<<2048, 256, 0, stream>>>(wt, (unsigned*)wb);
    k_sumsq_np<<<NROWS / SROWS, 256, 0, stream>>>(x,  xsqf);   // 512 blocks
    k_sumsq_np<<<QNUM  / SROWS, 256, 0, stream>>>(wt, wsqf);   // 256 blocks
    k_gemm_top2<<<8192, 256, 0, stream>>>(xb, wb, wsqf, part);
    k_rescore<<<4096, 256, 0, stream>>>(part, x, wt, wsqf, xsqf, outq, outi);
}

// Round 5
// 769.681 us; speedup vs baseline: 2.1081x; 2.1081x over previous
//
#include <hip/hip_runtime.h>
#include <stdint.h>

#define NROWS 16384
#define QNUM  8192
#define ED    512
#define BM    128
#define BN    128
#define KTILES 8           // K tiles of 64 elements
#define QBLKS  (QNUM / BN) // 64
#define DELTA  0.008f
#define ESLOT  17          // 16 top2-entries per row + 1 pad (uint4 units)

typedef __bf16 bf16x8 __attribute__((ext_vector_type(8)));
typedef float  f32x4  __attribute__((ext_vector_type(4)));

static __device__ __forceinline__ unsigned f2b1(float f) {
    unsigned u = __float_as_uint(f);
    return (u + 0x7FFFu + ((u >> 16) & 1u)) >> 16;   // RNE fp32 -> bf16
}
static __device__ __forceinline__ unsigned f2b2(float lo, float hi) {
    return f2b1(lo) | (f2b1(hi) << 16);
}

// keep top-2 (smallest val, tie -> smallest idx), branchless
static __device__ __forceinline__ void ins2(float& v1, int& q1, float& v2, int& q2,
                                            float s, int q) {
    const bool b1 = (s < v1) || (s == v1 && q < q1);
    const bool b2 = (s < v2) || (s == v2 && q < q2);
    const float nv2 = b1 ? v1 : (b2 ? s : v2);
    const int   nq2 = b1 ? q1 : (b2 ? q : q2);
    v1 = b1 ? s : v1;
    q1 = b1 ? q : q1;
    v2 = nv2; q2 = nq2;
}

// ---------------- prep: fp32 -> bf16 (RNE), 8 elems/thread ----------------
__global__ __launch_bounds__(256) void k_prep_bf16(const float* __restrict__ src,
                                                   unsigned* __restrict__ dst) {
    size_t t = (size_t)blockIdx.x * 256 + threadIdx.x;
    const float4* p = (const float4*)(src + t * 8);
    float4 a = p[0], b = p[1];
    uint4 o;
    o.x = f2b2(a.x, a.y); o.y = f2b2(a.z, a.w);
    o.z = f2b2(b.x, b.y); o.w = f2b2(b.z, b.w);
    ((uint4*)dst)[t] = o;
}

// ---------------- numpy-pairwise fp32 sum of squares per 512-row ----------------
#define SROWS 32
#define SSTRIDE 520
__global__ __launch_bounds__(256) void k_sumsq_np(const float* __restrict__ src,
                                                  float* __restrict__ dst) {
    __shared__ float ld[SROWS * SSTRIDE];
    const int t = threadIdx.x;
    const size_t base = (size_t)blockIdx.x * SROWS * ED;
    #pragma unroll
    for (int k = 0; k < 16; ++k) {
        int u = k * 256 + t;          // float4 index within the 32-row slab
        int row = u >> 7;             // 128 float4 per row
        int c4  = u & 127;
        float4 v = ((const float4*)(src + base))[u];
        float* d = ld + row * SSTRIDE + c4 * 4;
        d[0] = v.x; d[1] = v.y; d[2] = v.z; d[3] = v.w;
    }
    __syncthreads();
    const int row = t >> 3, j = t & 7;
    const float* a = ld + row * SSTRIDE;
    float B[4];
    #pragma unroll
    for (int b = 0; b < 4; ++b) {
        const float* p = a + b * 128 + j;
        float r = __fmul_rn(p[0], p[0]);
        #pragma unroll
        for (int i = 1; i < 16; ++i) {
            float q = p[8 * i];
            r = __fadd_rn(r, __fmul_rn(q, q));
        }
        float t1 = __fadd_rn(r,  __shfl_xor(r,  1, 64));
        float t2 = __fadd_rn(t1, __shfl_xor(t1, 2, 64));
        B[b]     = __fadd_rn(t2, __shfl_xor(t2, 4, 64));
    }
    if (j == 0)
        dst[(size_t)blockIdx.x * SROWS + row] =
            __fadd_rn(__fadd_rn(B[0], B[1]), __fadd_rn(B[2], B[3]));
}

// ---------------- phase 1: direct-to-register bf16 MFMA + cheap top-2 epilogue ----------------
// K-loop identical to R4 (control). Epilogue restructured: R3/R4 showed two
// different K-loop structures land within 4% -> shared epilogue dominated.
// Old: 256 dependency-chained __shfl_xor per wave (16 rows x 4 butterfly
// stages x 4 vals, ~60-80 cyc each). New: 16 shuffles total (one xor-8 stage),
// LDS transpose (34 KB padded), then 128 threads linearly scan 16 entries/row
// with independent ds_read_b128 (no chains).
__global__ __launch_bounds__(256) void k_gemm_top2(
        const unsigned short* __restrict__ xb,
        const unsigned short* __restrict__ wb,
        const float* __restrict__ wsqf,
        uint4* __restrict__ partial) {
    __shared__ uint4 ered[BM * ESLOT];   // 128*17*16 = 34,816 B

    const int t  = threadIdx.x;
    const int wv = t >> 6;
    const int l  = t & 63;
    const int c  = l & 15;   // MFMA col / A-row lane
    const int g  = l >> 4;   // MFMA quad
    const int RB = (wv >> 1) * 64;  // wave row base in block tile
    const int CB = (wv & 1) * 64;   // wave col base

    // XCD-aware swizzle: id%8 = XCD. XCD k owns q-panels [k*8,k*8+8) -> 1 MB of
    // B L2-resident per XCD; A-slabs reused 8x consecutively.
    const int id = blockIdx.x;
    const int qb = (id & 7) * 8 + ((id >> 3) & 7);  // 0..63
    const int rb = id >> 6;                          // 0..127
    const int q0 = qb * BN;
    const int r0 = rb * BM;

    f32x4 acc[4][4];
    #pragma unroll
    for (int i = 0; i < 4; ++i)
        #pragma unroll
        for (int j = 0; j < 4; ++j)
            acc[i][j] = (f32x4){0.f, 0.f, 0.f, 0.f};

    const unsigned short* ap = xb + (size_t)(r0 + RB + c) * ED;
    const unsigned short* bp = wb + (size_t)(q0 + CB + c) * ED;

    #pragma unroll
    for (int kt = 0; kt < KTILES; ++kt) {
        bf16x8 af[2][4], bfv[2][4];
        #pragma unroll
        for (int s = 0; s < 2; ++s) {
            const int ko = kt * 64 + (s * 4 + g) * 8;   // K element offset
            #pragma unroll
            for (int i = 0; i < 4; ++i)
                af[s][i] = *(const bf16x8*)(ap + (size_t)i * 16 * ED + ko);
            #pragma unroll
            for (int j = 0; j < 4; ++j)
                bfv[s][j] = *(const bf16x8*)(bp + (size_t)j * 16 * ED + ko);
        }
        #pragma unroll
        for (int s = 0; s < 2; ++s)
            #pragma unroll
            for (int i = 0; i < 4; ++i)
                #pragma unroll
                for (int j = 0; j < 4; ++j)
                    acc[i][j] = __builtin_amdgcn_mfma_f32_16x16x32_bf16(af[s][i], bfv[s][j], acc[i][j], 0, 0, 0);
    }

    float wsqv[4];
    #pragma unroll
    for (int j = 0; j < 4; ++j) wsqv[j] = wsqf[q0 + CB + j * 16 + c];

    #pragma unroll
    for (int i = 0; i < 4; ++i) {
        #pragma unroll
        for (int r = 0; r < 4; ++r) {
            float bv1 = 3.4e38f, bv2 = 3.4e38f;
            int   bq1 = 0x7fffffff, bq2 = 0x7fffffff;
            #pragma unroll
            for (int j = 0; j < 4; ++j) {
                const float s = fmaf(-2.0f, acc[i][j][r], wsqv[j]);
                const int   q = q0 + CB + j * 16 + c;
                ins2(bv1, bq1, bv2, bq2, s, q);
            }
            // single xor-8 merge: lanes c and c^8 end identical; c<8 writes
            {
                float ov1 = __shfl_xor(bv1, 8, 64);
                int   oq1 = __shfl_xor(bq1, 8, 64);
                float ov2 = __shfl_xor(bv2, 8, 64);
                int   oq2 = __shfl_xor(bq2, 8, 64);
                ins2(bv1, bq1, bv2, bq2, ov1, oq1);
                ins2(bv1, bq1, bv2, bq2, ov2, oq2);
            }
            if (c < 8) {
                const int row = RB + i * 16 + g * 4 + r;
                ered[row * ESLOT + (wv & 1) * 8 + c] =
                    make_uint4(__float_as_uint(bv1), (unsigned)bq1,
                               __float_as_uint(bv2), (unsigned)bq2);
            }
        }
    }
    __syncthreads();
    if (t < BM) {
        const uint4* e = &ered[t * ESLOT];
        uint4 E[16];
        #pragma unroll
        for (int k = 0; k < 16; ++k) E[k] = e[k];   // independent ds_read_b128s
        float av1 = 3.4e38f, av2 = 3.4e38f;
        int   aq1 = 0x7fffffff, aq2 = 0x7fffffff;
        #pragma unroll
        for (int k = 0; k < 16; ++k) {
            ins2(av1, aq1, av2, aq2, __uint_as_float(E[k].x), (int)E[k].y);
            ins2(av1, aq1, av2, aq2, __uint_as_float(E[k].z), (int)E[k].w);
        }
        partial[(size_t)(r0 + t) * QBLKS + qb] =
            make_uint4(__float_as_uint(av1), (unsigned)aq1, __float_as_uint(av2), (unsigned)aq2);
    }
}

// ---------------- phase 2: fp32-emulated (numpy semantics) rescore + gather ----------------
__global__ __launch_bounds__(256) void k_rescore(
        const uint4* __restrict__ partial,
        const float* __restrict__ x,
        const float* __restrict__ wt,
        const float* __restrict__ wsqf,
        const float* __restrict__ xsqf,
        float* __restrict__ outq,
        float* __restrict__ outi) {
    const int wv = threadIdx.x >> 6, l = threadIdx.x & 63;
    const int row = blockIdx.x * 4 + wv;

    uint4 p = partial[(size_t)row * QBLKS + l];
    float v1 = __uint_as_float(p.x), v2 = __uint_as_float(p.z);
    int   q1 = (int)p.y, q2 = (int)p.w;

    float gm = v1;
    #pragma unroll
    for (int m = 1; m < 64; m <<= 1) gm = fminf(gm, __shfl_xor(gm, m, 64));
    const float thr = gm + DELTA;

    const float4* xp = (const float4*)(x + (size_t)row * ED + l * 8);
    const float4 xa = xp[0], xbv = xp[1];
    const float xsq = xsqf[row];

    float bestv = 3.4e38f; int bestq = 0x7fffffff;
    unsigned long long mm1 = __ballot(v1 <= thr);
    unsigned long long mm2 = __ballot(v2 <= thr);
    #pragma unroll 1
    for (int slot = 0; slot < 2; ++slot) {
        unsigned long long mm = slot ? mm2 : mm1;
        while (mm) {
            const int ln = __ffsll(mm) - 1;
            mm &= mm - 1;
            const int q = __shfl(slot ? q2 : q1, ln, 64);
            const float4* wp = (const float4*)(wt + (size_t)q * ED + l * 8);
            const float4 wa = wp[0], wbv = wp[1];
            double d = (double)xa.x * wa.x + (double)xa.y * wa.y
                     + (double)xa.z * wa.z + (double)xa.w * wa.w
                     + (double)xbv.x * wbv.x + (double)xbv.y * wbv.y
                     + (double)xbv.z * wbv.z + (double)xbv.w * wbv.w;
            #pragma unroll
            for (int m = 1; m < 64; m <<= 1) d += __shfl_xor(d, m, 64);
            // numpy fp32 semantics: fl32( fl32(x_sq - 2*dot) + w_sq ), first-occurrence argmin
            const float dotf = (float)d;
            const float t1 = __fadd_rn(xsq, __fmul_rn(-2.0f, dotf));
            const float sc = __fadd_rn(t1, wsqf[q]);
            if (sc < bestv || (sc == bestv && q < bestq)) { bestv = sc; bestq = q; }
        }
    }
    const float4* wp = (const float4*)(wt + (size_t)bestq * ED + l * 8);
    float4* op = (float4*)(outq + (size_t)row * ED + l * 8);
    op[0] = wp[0]; op[1] = wp[1];
    if (l == 0) outi[row] = (float)bestq;
}

extern "C" void kernel_launch(void* const* d_in, const int* in_sizes, int n_in,
                              void* d_out, int out_size, void* d_ws, size_t ws_size,
                              hipStream_t stream) {
    (void)in_sizes; (void)n_in; (void)out_size; (void)ws_size;
    const float* x  = (const float*)d_in[0];
    const float* wt = (const float*)d_in[1];

    char* ws = (char*)d_ws;
    unsigned short* xb   = (unsigned short*)ws;               // 16,777,216 B
    unsigned short* wb   = (unsigned short*)(ws + 16777216);  //  8,388,608 B
    float*          wsqf = (float*) (ws + 25165824);          //     32,768 B
    float*          xsqf = (float*) (ws + 25198592);          //     65,536 B
    uint4*          part = (uint4*) (ws + 25264128);          // 16,777,216 B  (total ~40.1 MB)

    float* outq = (float*)d_out;
    float* outi = outq + (size_t)NROWS * ED;

    k_prep_bf16<<<4096, 256, 0, stream>>>(x,  (unsigned*)xb);
    k_prep_bf16<<<2048, 256, 0, stream>>>(wt, (unsigned*)wb);
    k_sumsq_np<<<NROWS / SROWS, 256, 0, stream>>>(x,  xsqf);   // 512 blocks
    k_sumsq_np<<<QNUM  / SROWS, 256, 0, stream>>>(wt, wsqf);   // 256 blocks
    k_gemm_top2<<<8192, 256, 0, stream>>>(xb, wb, wsqf, part);
    k_rescore<<<4096, 256, 0, stream>>>(part, x, wt, wsqf, xsqf, outq, outi);
}

// Round 6
// 647.779 us; speedup vs baseline: 2.5048x; 1.1882x over previous
//
#include <hip/hip_runtime.h>
#include <stdint.h>

#define NROWS 16384
#define QNUM  8192
#define ED    512
#define BM    128
#define BN    128
#define KTILES 8           // K tiles of 64 elements
#define QBLKS  (QNUM / BN) // 64
#define DELTA  0.008f
#define ESLOT  17          // 16 top2-entries per row + 1 pad (uint4 units)

typedef __bf16 bf16x8 __attribute__((ext_vector_type(8)));
typedef float  f32x4  __attribute__((ext_vector_type(4)));

static __device__ __forceinline__ unsigned f2b1(float f) {
    unsigned u = __float_as_uint(f);
    return (u + 0x7FFFu + ((u >> 16) & 1u)) >> 16;   // RNE fp32 -> bf16
}
static __device__ __forceinline__ unsigned f2b2(float lo, float hi) {
    return f2b1(lo) | (f2b1(hi) << 16);
}

// keep top-2 (smallest val, tie -> smallest idx), branchless
static __device__ __forceinline__ void ins2(float& v1, int& q1, float& v2, int& q2,
                                            float s, int q) {
    const bool b1 = (s < v1) || (s == v1 && q < q1);
    const bool b2 = (s < v2) || (s == v2 && q < q2);
    const float nv2 = b1 ? v1 : (b2 ? s : v2);
    const int   nq2 = b1 ? q1 : (b2 ? q : q2);
    v1 = b1 ? s : v1;
    q1 = b1 ? q : q1;
    v2 = nv2; q2 = nq2;
}

// ---------------- prep: fp32 -> bf16 (RNE), 8 elems/thread ----------------
__global__ __launch_bounds__(256) void k_prep_bf16(const float* __restrict__ src,
                                                   unsigned* __restrict__ dst) {
    size_t t = (size_t)blockIdx.x * 256 + threadIdx.x;
    const float4* p = (const float4*)(src + t * 8);
    float4 a = p[0], b = p[1];
    uint4 o;
    o.x = f2b2(a.x, a.y); o.y = f2b2(a.z, a.w);
    o.z = f2b2(b.x, b.y); o.w = f2b2(b.z, b.w);
    ((uint4*)dst)[t] = o;
}

// ---------------- numpy-pairwise fp32 sum of squares per 512-row ----------------
#define SROWS 32
#define SSTRIDE 520
__global__ __launch_bounds__(256) void k_sumsq_np(const float* __restrict__ src,
                                                  float* __restrict__ dst) {
    __shared__ float ld[SROWS * SSTRIDE];
    const int t = threadIdx.x;
    const size_t base = (size_t)blockIdx.x * SROWS * ED;
    #pragma unroll
    for (int k = 0; k < 16; ++k) {
        int u = k * 256 + t;          // float4 index within the 32-row slab
        int row = u >> 7;             // 128 float4 per row
        int c4  = u & 127;
        float4 v = ((const float4*)(src + base))[u];
        float* d = ld + row * SSTRIDE + c4 * 4;
        d[0] = v.x; d[1] = v.y; d[2] = v.z; d[3] = v.w;
    }
    __syncthreads();
    const int row = t >> 3, j = t & 7;
    const float* a = ld + row * SSTRIDE;
    float B[4];
    #pragma unroll
    for (int b = 0; b < 4; ++b) {
        const float* p = a + b * 128 + j;
        float r = __fmul_rn(p[0], p[0]);
        #pragma unroll
        for (int i = 1; i < 16; ++i) {
            float q = p[8 * i];
            r = __fadd_rn(r, __fmul_rn(q, q));
        }
        float t1 = __fadd_rn(r,  __shfl_xor(r,  1, 64));
        float t2 = __fadd_rn(t1, __shfl_xor(t1, 2, 64));
        B[b]     = __fadd_rn(t2, __shfl_xor(t2, 4, 64));
    }
    if (j == 0)
        dst[(size_t)blockIdx.x * SROWS + row] =
            __fadd_rn(__fadd_rn(B[0], B[1]), __fadd_rn(B[2], B[3]));
}

// ---------------- phase 1: register-pipelined bf16 MFMA + top-2 epilogue ----------------
// R5 left an 80% stall in the K-loop: at VGPR_Count=88 the compiler couldn't
// hold two iterations' fragments (64 VGPRs each), so every kt ate a full
// exposed vmcnt(0) L2 round-trip. Fix: __launch_bounds__(256,2) raises the
// VGPR cap to 256; manual 1-deep double-buffered prefetch keeps 16 loads in
// flight across each MFMA block (waits at vmcnt(16), never 0 — AITER pattern).
// Epilogue unchanged from R5 (control).
__global__ __launch_bounds__(256, 2) void k_gemm_top2(
        const unsigned short* __restrict__ xb,
        const unsigned short* __restrict__ wb,
        const float* __restrict__ wsqf,
        uint4* __restrict__ partial) {
    __shared__ uint4 ered[BM * ESLOT];   // 128*17*16 = 34,816 B

    const int t  = threadIdx.x;
    const int wv = t >> 6;
    const int l  = t & 63;
    const int c  = l & 15;   // MFMA col / A-row lane
    const int g  = l >> 4;   // MFMA quad
    const int RB = (wv >> 1) * 64;  // wave row base in block tile
    const int CB = (wv & 1) * 64;   // wave col base

    // XCD-aware swizzle: id%8 = XCD. XCD k owns q-panels [k*8,k*8+8) -> 1 MB of
    // B L2-resident per XCD; A-slabs reused 8x consecutively.
    const int id = blockIdx.x;
    const int qb = (id & 7) * 8 + ((id >> 3) & 7);  // 0..63
    const int rb = id >> 6;                          // 0..127
    const int q0 = qb * BN;
    const int r0 = rb * BM;

    f32x4 acc[4][4];
    #pragma unroll
    for (int i = 0; i < 4; ++i)
        #pragma unroll
        for (int j = 0; j < 4; ++j)
            acc[i][j] = (f32x4){0.f, 0.f, 0.f, 0.f};

    const unsigned short* ap = xb + (size_t)(r0 + RB + c) * ED;
    const unsigned short* bp = wb + (size_t)(q0 + CB + c) * ED;

    bf16x8 af[2][2][4], bfv[2][2][4];   // [buf][s][i]

    // prologue: kt=0 into buf 0
    #pragma unroll
    for (int s = 0; s < 2; ++s) {
        const int ko = (s * 4 + g) * 8;
        #pragma unroll
        for (int i = 0; i < 4; ++i)
            af[0][s][i] = *(const bf16x8*)(ap + (size_t)i * 16 * ED + ko);
        #pragma unroll
        for (int j = 0; j < 4; ++j)
            bfv[0][s][j] = *(const bf16x8*)(bp + (size_t)j * 16 * ED + ko);
    }

    #pragma unroll
    for (int kt = 0; kt < KTILES; ++kt) {
        const int cur = kt & 1, nxt = cur ^ 1;
        if (kt + 1 < KTILES) {   // issue next-iteration loads BEFORE this iteration's MFMAs
            #pragma unroll
            for (int s = 0; s < 2; ++s) {
                const int ko = (kt + 1) * 64 + (s * 4 + g) * 8;
                #pragma unroll
                for (int i = 0; i < 4; ++i)
                    af[nxt][s][i] = *(const bf16x8*)(ap + (size_t)i * 16 * ED + ko);
                #pragma unroll
                for (int j = 0; j < 4; ++j)
                    bfv[nxt][s][j] = *(const bf16x8*)(bp + (size_t)j * 16 * ED + ko);
            }
        }
        #pragma unroll
        for (int s = 0; s < 2; ++s)
            #pragma unroll
            for (int i = 0; i < 4; ++i)
                #pragma unroll
                for (int j = 0; j < 4; ++j)
                    acc[i][j] = __builtin_amdgcn_mfma_f32_16x16x32_bf16(af[cur][s][i], bfv[cur][s][j], acc[i][j], 0, 0, 0);
    }

    float wsqv[4];
    #pragma unroll
    for (int j = 0; j < 4; ++j) wsqv[j] = wsqf[q0 + CB + j * 16 + c];

    #pragma unroll
    for (int i = 0; i < 4; ++i) {
        #pragma unroll
        for (int r = 0; r < 4; ++r) {
            float bv1 = 3.4e38f, bv2 = 3.4e38f;
            int   bq1 = 0x7fffffff, bq2 = 0x7fffffff;
            #pragma unroll
            for (int j = 0; j < 4; ++j) {
                const float s = fmaf(-2.0f, acc[i][j][r], wsqv[j]);
                const int   q = q0 + CB + j * 16 + c;
                ins2(bv1, bq1, bv2, bq2, s, q);
            }
            // single xor-8 merge: lanes c and c^8 end identical; c<8 writes
            {
                float ov1 = __shfl_xor(bv1, 8, 64);
                int   oq1 = __shfl_xor(bq1, 8, 64);
                float ov2 = __shfl_xor(bv2, 8, 64);
                int   oq2 = __shfl_xor(bq2, 8, 64);
                ins2(bv1, bq1, bv2, bq2, ov1, oq1);
                ins2(bv1, bq1, bv2, bq2, ov2, oq2);
            }
            if (c < 8) {
                const int row = RB + i * 16 + g * 4 + r;
                ered[row * ESLOT + (wv & 1) * 8 + c] =
                    make_uint4(__float_as_uint(bv1), (unsigned)bq1,
                               __float_as_uint(bv2), (unsigned)bq2);
            }
        }
    }
    __syncthreads();
    if (t < BM) {
        const uint4* e = &ered[t * ESLOT];
        uint4 E[16];
        #pragma unroll
        for (int k = 0; k < 16; ++k) E[k] = e[k];   // independent ds_read_b128s
        float av1 = 3.4e38f, av2 = 3.4e38f;
        int   aq1 = 0x7fffffff, aq2 = 0x7fffffff;
        #pragma unroll
        for (int k = 0; k < 16; ++k) {
            ins2(av1, aq1, av2, aq2, __uint_as_float(E[k].x), (int)E[k].y);
            ins2(av1, aq1, av2, aq2, __uint_as_float(E[k].z), (int)E[k].w);
        }
        partial[(size_t)(r0 + t) * QBLKS + qb] =
            make_uint4(__float_as_uint(av1), (unsigned)aq1, __float_as_uint(av2), (unsigned)aq2);
    }
}

// ---------------- phase 2: fp32-emulated (numpy semantics) rescore + gather ----------------
__global__ __launch_bounds__(256) void k_rescore(
        const uint4* __restrict__ partial,
        const float* __restrict__ x,
        const float* __restrict__ wt,
        const float* __restrict__ wsqf,
        const float* __restrict__ xsqf,
        float* __restrict__ outq,
        float* __restrict__ outi) {
    const int wv = threadIdx.x >> 6, l = threadIdx.x & 63;
    const int row = blockIdx.x * 4 + wv;

    uint4 p = partial[(size_t)row * QBLKS + l];
    float v1 = __uint_as_float(p.x), v2 = __uint_as_float(p.z);
    int   q1 = (int)p.y, q2 = (int)p.w;

    float gm = v1;
    #pragma unroll
    for (int m = 1; m < 64; m <<= 1) gm = fminf(gm, __shfl_xor(gm, m, 64));
    const float thr = gm + DELTA;

    const float4* xp = (const float4*)(x + (size_t)row * ED + l * 8);
    const float4 xa = xp[0], xbv = xp[1];
    const float xsq = xsqf[row];

    float bestv = 3.4e38f; int bestq = 0x7fffffff;
    unsigned long long mm1 = __ballot(v1 <= thr);
    unsigned long long mm2 = __ballot(v2 <= thr);
    #pragma unroll 1
    for (int slot = 0; slot < 2; ++slot) {
        unsigned long long mm = slot ? mm2 : mm1;
        while (mm) {
            const int ln = __ffsll(mm) - 1;
            mm &= mm - 1;
            const int q = __shfl(slot ? q2 : q1, ln, 64);
            const float4* wp = (const float4*)(wt + (size_t)q * ED + l * 8);
            const float4 wa = wp[0], wbv = wp[1];
            double d = (double)xa.x * wa.x + (double)xa.y * wa.y
                     + (double)xa.z * wa.z + (double)xa.w * wa.w
                     + (double)xbv.x * wbv.x + (double)xbv.y * wbv.y
                     + (double)xbv.z * wbv.z + (double)xbv.w * wbv.w;
            #pragma unroll
            for (int m = 1; m < 64; m <<= 1) d += __shfl_xor(d, m, 64);
            // numpy fp32 semantics: fl32( fl32(x_sq - 2*dot) + w_sq ), first-occurrence argmin
            const float dotf = (float)d;
            const float t1 = __fadd_rn(xsq, __fmul_rn(-2.0f, dotf));
            const float sc = __fadd_rn(t1, wsqf[q]);
            if (sc < bestv || (sc == bestv && q < bestq)) { bestv = sc; bestq = q; }
        }
    }
    const float4* wp = (const float4*)(wt + (size_t)bestq * ED + l * 8);
    float4* op = (float4*)(outq + (size_t)row * ED + l * 8);
    op[0] = wp[0]; op[1] = wp[1];
    if (l == 0) outi[row] = (float)bestq;
}

extern "C" void kernel_launch(void* const* d_in, const int* in_sizes, int n_in,
                              void* d_out, int out_size, void* d_ws, size_t ws_size,
                              hipStream_t stream) {
    (void)in_sizes; (void)n_in; (void)out_size; (void)ws_size;
    const float* x  = (const float*)d_in[0];
    const float* wt = (const float*)d_in[1];

    char* ws = (char*)d_ws;
    unsigned short* xb   = (unsigned short*)ws;               // 16,777,216 B
    unsigned short* wb   = (unsigned short*)(ws + 16777216);  //  8,388,608 B
    float*          wsqf = (float*) (ws + 25165824);          //     32,768 B
    float*          xsqf = (float*) (ws + 25198592);          //     65,536 B
    uint4*          part = (uint4*) (ws + 25264128);          // 16,777,216 B  (total ~40.1 MB)

    float* outq = (float*)d_out;
    float* outi = outq + (size_t)NROWS * ED;

    k_prep_bf16<<<4096, 256, 0, stream>>>(x,  (unsigned*)xb);
    k_prep_bf16<<<2048, 256, 0, stream>>>(wt, (unsigned*)wb);
    k_sumsq_np<<<NROWS / SROWS, 256, 0, stream>>>(x,  xsqf);   // 512 blocks
    k_sumsq_np<<<QNUM  / SROWS, 256, 0, stream>>>(wt, wsqf);   // 256 blocks
    k_gemm_top2<<<8192, 256, 0, stream>>>(xb, wb, wsqf, part);
    k_rescore<<<4096, 256, 0, stream>>>(part, x, wt, wsqf, xsqf, outq, outi);
}

// Round 7
// 477.962 us; speedup vs baseline: 3.3948x; 1.3553x over previous
//
#include <hip/hip_runtime.h>
#include <stdint.h>

#define NROWS 16384
#define QNUM  8192
#define ED    512
#define BM    128
#define BN    128
#define KTILES 8           // K tiles of 64 elements
#define QBLKS  (QNUM / BN) // 64
#define DELTA  0.008f
#define ESLOT  17          // 16 top2-entries per row + 1 pad (uint4 units)
#define KCH    (ED / 32)   // 16 K-chunks (32 elems each) per row-tile

typedef __bf16 bf16x8 __attribute__((ext_vector_type(8)));
typedef float  f32x4  __attribute__((ext_vector_type(4)));

static __device__ __forceinline__ unsigned f2b1(float f) {
    unsigned u = __float_as_uint(f);
    return (u + 0x7FFFu + ((u >> 16) & 1u)) >> 16;   // RNE fp32 -> bf16
}
static __device__ __forceinline__ unsigned f2b2(float lo, float hi) {
    return f2b1(lo) | (f2b1(hi) << 16);
}

// keep top-2 (smallest val, tie -> smallest idx), branchless
static __device__ __forceinline__ void ins2(float& v1, int& q1, float& v2, int& q2,
                                            float s, int q) {
    const bool b1 = (s < v1) || (s == v1 && q < q1);
    const bool b2 = (s < v2) || (s == v2 && q < q2);
    const float nv2 = b1 ? v1 : (b2 ? s : v2);
    const int   nq2 = b1 ? q1 : (b2 ? q : q2);
    v1 = b1 ? s : v1;
    q1 = b1 ? q : q1;
    v2 = nv2; q2 = nq2;
}

// ---------------- prep: fp32 -> bf16 (RNE) into MFMA-fragment-tiled layout ----------------
// Chunk (rt, kc) = rows rt*16..+15 x K kc*32..+31, 1 KB. Granule l within a chunk
// holds row rt*16+(l&15), K (kc*32+(l>>4)*8 .. +8) — exactly lane l's fragment, so
// every K-loop load is one wave-contiguous 1 KB burst (R6 loads touched 16
// scattered 64 B lines per instruction -> TA serialization).
__global__ __launch_bounds__(256) void k_prep_perm(const float* __restrict__ src,
                                                   uint4* __restrict__ dst) {
    size_t t = (size_t)blockIdx.x * 256 + threadIdx.x;  // one 8-elem granule per thread
    const float4* p = (const float4*)(src + t * 8);
    float4 a = p[0], b = p[1];
    uint4 o;
    o.x = f2b2(a.x, a.y); o.y = f2b2(a.z, a.w);
    o.z = f2b2(b.x, b.y); o.w = f2b2(b.z, b.w);
    const int row = (int)(t >> 6);        // ED/8 = 64 granules per row
    const int kg  = (int)(t & 63);        // granule index within row
    const int kc  = kg >> 2;              // K-chunk (32 elems)
    const int g   = kg & 3;               // K-subchunk (8 elems)
    const int rt  = row >> 4, c = row & 15;
    dst[((size_t)rt * KCH + kc) * 64 + g * 16 + c] = o;
}

// ---------------- numpy-pairwise fp32 sum of squares per 512-row ----------------
#define SROWS 32
#define SSTRIDE 520
__global__ __launch_bounds__(256) void k_sumsq_np(const float* __restrict__ src,
                                                  float* __restrict__ dst) {
    __shared__ float ld[SROWS * SSTRIDE];
    const int t = threadIdx.x;
    const size_t base = (size_t)blockIdx.x * SROWS * ED;
    #pragma unroll
    for (int k = 0; k < 16; ++k) {
        int u = k * 256 + t;          // float4 index within the 32-row slab
        int row = u >> 7;             // 128 float4 per row
        int c4  = u & 127;
        float4 v = ((const float4*)(src + base))[u];
        float* d = ld + row * SSTRIDE + c4 * 4;
        d[0] = v.x; d[1] = v.y; d[2] = v.z; d[3] = v.w;
    }
    __syncthreads();
    const int row = t >> 3, j = t & 7;
    const float* a = ld + row * SSTRIDE;
    float B[4];
    #pragma unroll
    for (int b = 0; b < 4; ++b) {
        const float* p = a + b * 128 + j;
        float r = __fmul_rn(p[0], p[0]);
        #pragma unroll
        for (int i = 1; i < 16; ++i) {
            float q = p[8 * i];
            r = __fadd_rn(r, __fmul_rn(q, q));
        }
        float t1 = __fadd_rn(r,  __shfl_xor(r,  1, 64));
        float t2 = __fadd_rn(t1, __shfl_xor(t1, 2, 64));
        B[b]     = __fadd_rn(t2, __shfl_xor(t2, 4, 64));
    }
    if (j == 0)
        dst[(size_t)blockIdx.x * SROWS + row] =
            __fadd_rn(__fadd_rn(B[0], B[1]), __fadd_rn(B[2], B[3]));
}

// ---------------- phase 1: register-pipelined bf16 MFMA + top-2 epilogue ----------------
// K-loop/epilogue structure = R6 (control); only the load addressing changed to
// the fragment-tiled layout (wave-contiguous 1 KB per load instruction).
__global__ __launch_bounds__(256, 2) void k_gemm_top2(
        const bf16x8* __restrict__ xb,    // fragment-tiled
        const bf16x8* __restrict__ wb,    // fragment-tiled
        const float* __restrict__ wsqf,
        uint4* __restrict__ partial) {
    __shared__ uint4 ered[BM * ESLOT];   // 128*17*16 = 34,816 B

    const int t  = threadIdx.x;
    const int wv = t >> 6;
    const int l  = t & 63;
    const int c  = l & 15;   // MFMA col / A-row lane
    const int g  = l >> 4;   // MFMA quad
    const int RB = (wv >> 1) * 64;  // wave row base in block tile
    const int CB = (wv & 1) * 64;   // wave col base

    // XCD-aware swizzle: id%8 = XCD. XCD k owns q-panels [k*8,k*8+8) -> 1 MB of
    // B L2-resident per XCD; A-slabs reused 8x consecutively.
    const int id = blockIdx.x;
    const int qb = (id & 7) * 8 + ((id >> 3) & 7);  // 0..63
    const int rb = id >> 6;                          // 0..127
    const int q0 = qb * BN;
    const int r0 = rb * BM;

    f32x4 acc[4][4];
    #pragma unroll
    for (int i = 0; i < 4; ++i)
        #pragma unroll
        for (int j = 0; j < 4; ++j)
            acc[i][j] = (f32x4){0.f, 0.f, 0.f, 0.f};

    // granule base: chunk (rt, kc) at index (rt*KCH + kc)*64 + l
    const bf16x8* ga = xb + ((size_t)((r0 + RB) >> 4) * KCH) * 64 + l;
    const bf16x8* gb = wb + ((size_t)((q0 + CB) >> 4) * KCH) * 64 + l;

    bf16x8 af[2][2][4], bfv[2][2][4];   // [buf][s][i]

    // prologue: kt=0 into buf 0
    #pragma unroll
    for (int s = 0; s < 2; ++s) {
        #pragma unroll
        for (int i = 0; i < 4; ++i)
            af[0][s][i] = ga[((size_t)i * KCH + s) * 64];
        #pragma unroll
        for (int j = 0; j < 4; ++j)
            bfv[0][s][j] = gb[((size_t)j * KCH + s) * 64];
    }

    #pragma unroll
    for (int kt = 0; kt < KTILES; ++kt) {
        const int cur = kt & 1, nxt = cur ^ 1;
        if (kt + 1 < KTILES) {   // issue next-iteration loads BEFORE this iteration's MFMAs
            #pragma unroll
            for (int s = 0; s < 2; ++s) {
                const int kcg = 2 * (kt + 1) + s;
                #pragma unroll
                for (int i = 0; i < 4; ++i)
                    af[nxt][s][i] = ga[((size_t)i * KCH + kcg) * 64];
                #pragma unroll
                for (int j = 0; j < 4; ++j)
                    bfv[nxt][s][j] = gb[((size_t)j * KCH + kcg) * 64];
            }
        }
        #pragma unroll
        for (int s = 0; s < 2; ++s)
            #pragma unroll
            for (int i = 0; i < 4; ++i)
                #pragma unroll
                for (int j = 0; j < 4; ++j)
                    acc[i][j] = __builtin_amdgcn_mfma_f32_16x16x32_bf16(af[cur][s][i], bfv[cur][s][j], acc[i][j], 0, 0, 0);
    }

    float wsqv[4];
    #pragma unroll
    for (int j = 0; j < 4; ++j) wsqv[j] = wsqf[q0 + CB + j * 16 + c];

    #pragma unroll
    for (int i = 0; i < 4; ++i) {
        #pragma unroll
        for (int r = 0; r < 4; ++r) {
            float bv1 = 3.4e38f, bv2 = 3.4e38f;
            int   bq1 = 0x7fffffff, bq2 = 0x7fffffff;
            #pragma unroll
            for (int j = 0; j < 4; ++j) {
                const float s = fmaf(-2.0f, acc[i][j][r], wsqv[j]);
                const int   q = q0 + CB + j * 16 + c;
                ins2(bv1, bq1, bv2, bq2, s, q);
            }
            // single xor-8 merge: lanes c and c^8 end identical; c<8 writes
            {
                float ov1 = __shfl_xor(bv1, 8, 64);
                int   oq1 = __shfl_xor(bq1, 8, 64);
                float ov2 = __shfl_xor(bv2, 8, 64);
                int   oq2 = __shfl_xor(bq2, 8, 64);
                ins2(bv1, bq1, bv2, bq2, ov1, oq1);
                ins2(bv1, bq1, bv2, bq2, ov2, oq2);
            }
            if (c < 8) {
                const int row = RB + i * 16 + g * 4 + r;
                ered[row * ESLOT + (wv & 1) * 8 + c] =
                    make_uint4(__float_as_uint(bv1), (unsigned)bq1,
                               __float_as_uint(bv2), (unsigned)bq2);
            }
        }
    }
    __syncthreads();
    if (t < BM) {
        const uint4* e = &ered[t * ESLOT];
        uint4 E[16];
        #pragma unroll
        for (int k = 0; k < 16; ++k) E[k] = e[k];   // independent ds_read_b128s
        float av1 = 3.4e38f, av2 = 3.4e38f;
        int   aq1 = 0x7fffffff, aq2 = 0x7fffffff;
        #pragma unroll
        for (int k = 0; k < 16; ++k) {
            ins2(av1, aq1, av2, aq2, __uint_as_float(E[k].x), (int)E[k].y);
            ins2(av1, aq1, av2, aq2, __uint_as_float(E[k].z), (int)E[k].w);
        }
        partial[(size_t)(r0 + t) * QBLKS + qb] =
            make_uint4(__float_as_uint(av1), (unsigned)aq1, __float_as_uint(av2), (unsigned)aq2);
    }
}

// ---------------- phase 2: fp32-emulated (numpy semantics) rescore + gather ----------------
__global__ __launch_bounds__(256) void k_rescore(
        const uint4* __restrict__ partial,
        const float* __restrict__ x,
        const float* __restrict__ wt,
        const float* __restrict__ wsqf,
        const float* __restrict__ xsqf,
        float* __restrict__ outq,
        float* __restrict__ outi) {
    const int wv = threadIdx.x >> 6, l = threadIdx.x & 63;
    const int row = blockIdx.x * 4 + wv;

    uint4 p = partial[(size_t)row * QBLKS + l];
    float v1 = __uint_as_float(p.x), v2 = __uint_as_float(p.z);
    int   q1 = (int)p.y, q2 = (int)p.w;

    float gm = v1;
    #pragma unroll
    for (int m = 1; m < 64; m <<= 1) gm = fminf(gm, __shfl_xor(gm, m, 64));
    const float thr = gm + DELTA;

    const float4* xp = (const float4*)(x + (size_t)row * ED + l * 8);
    const float4 xa = xp[0], xbv = xp[1];
    const float xsq = xsqf[row];

    float bestv = 3.4e38f; int bestq = 0x7fffffff;
    unsigned long long mm1 = __ballot(v1 <= thr);
    unsigned long long mm2 = __ballot(v2 <= thr);
    #pragma unroll 1
    for (int slot = 0; slot < 2; ++slot) {
        unsigned long long mm = slot ? mm2 : mm1;
        while (mm) {
            const int ln = __ffsll(mm) - 1;
            mm &= mm - 1;
            const int q = __shfl(slot ? q2 : q1, ln, 64);
            const float4* wp = (const float4*)(wt + (size_t)q * ED + l * 8);
            const float4 wa = wp[0], wbv = wp[1];
            double d = (double)xa.x * wa.x + (double)xa.y * wa.y
                     + (double)xa.z * wa.z + (double)xa.w * wa.w
                     + (double)xbv.x * wbv.x + (double)xbv.y * wbv.y
                     + (double)xbv.z * wbv.z + (double)xbv.w * wbv.w;
            #pragma unroll
            for (int m = 1; m < 64; m <<= 1) d += __shfl_xor(d, m, 64);
            // numpy fp32 semantics: fl32( fl32(x_sq - 2*dot) + w_sq ), first-occurrence argmin
            const float dotf = (float)d;
            const float t1 = __fadd_rn(xsq, __fmul_rn(-2.0f, dotf));
            const float sc = __fadd_rn(t1, wsqf[q]);
            if (sc < bestv || (sc == bestv && q < bestq)) { bestv = sc; bestq = q; }
        }
    }
    const float4* wp = (const float4*)(wt + (size_t)bestq * ED + l * 8);
    float4* op = (float4*)(outq + (size_t)row * ED + l * 8);
    op[0] = wp[0]; op[1] = wp[1];
    if (l == 0) outi[row] = (float)bestq;
}

extern "C" void kernel_launch(void* const* d_in, const int* in_sizes, int n_in,
                              void* d_out, int out_size, void* d_ws, size_t ws_size,
                              hipStream_t stream) {
    (void)in_sizes; (void)n_in; (void)out_size; (void)ws_size;
    const float* x  = (const float*)d_in[0];
    const float* wt = (const float*)d_in[1];

    char* ws = (char*)d_ws;
    uint4*  xb   = (uint4*)ws;                       // 16,777,216 B (fragment-tiled)
    uint4*  wb   = (uint4*)(ws + 16777216);          //  8,388,608 B (fragment-tiled)
    float*  wsqf = (float*) (ws + 25165824);         //     32,768 B
    float*  xsqf = (float*) (ws + 25198592);         //     65,536 B
    uint4*  part = (uint4*) (ws + 25264128);         // 16,777,216 B  (total ~40.1 MB)

    float* outq = (float*)d_out;
    float* outi = outq + (size_t)NROWS * ED;

    k_prep_perm<<<4096, 256, 0, stream>>>(x,  xb);
    k_prep_perm<<<2048, 256, 0, stream>>>(wt, wb);
    k_sumsq_np<<<NROWS / SROWS, 256, 0, stream>>>(x,  xsqf);   // 512 blocks
    k_sumsq_np<<<QNUM  / SROWS, 256, 0, stream>>>(wt, wsqf);   // 256 blocks
    k_gemm_top2<<<8192, 256, 0, stream>>>((const bf16x8*)xb, (const bf16x8*)wb, wsqf, part);
    k_rescore<<<4096, 256, 0, stream>>>(part, x, wt, wsqf, xsqf, outq, outi);
}